// Round 10
// baseline (171.886 us; speedup 1.0000x reference)
//
#include <hip/hip_runtime.h>
#include <math.h>

#define NT 512   // threads per block; 512 blocks (one per channel h)

// Packed f32 pair: LLVM lowers arithmetic on this to v_pk_*_f32 (VOP3P) on gfx950.
typedef float v2 __attribute__((ext_vector_type(2)));

__device__ __forceinline__ v2 vrot(v2 a){ return (v2){-a.y, a.x}; }            // i*a
__device__ __forceinline__ v2 vconj(v2 a){ return (v2){a.x, -a.y}; }
__device__ __forceinline__ v2 vcmul(v2 a, v2 b){ return a.x*b + a.y*vrot(b); } // complex mul: 2 pk_fma
__device__ __forceinline__ v2 vfma1(float s, v2 v, v2 acc){                    // acc + s*v: 1 pk_fma
    return (v2){ __builtin_fmaf(s, v.x, acc.x), __builtin_fmaf(s, v.y, acc.y) };
}

// XOR bank swizzle: float2 elements -> bank = (2e)%32 depends on e mod 16.
__device__ __forceinline__ int SW(int e){ return e ^ (((e>>5) ^ (e>>9)) & 15); }

// base-8 digit reversal of a 12-bit index
__device__ __forceinline__ int d8r4(int x){
    return ((x&7)<<9) | (((x>>3)&7)<<6) | (((x>>6)&7)<<3) | ((x>>9)&7);
}
// base-8 digit reversal of a 9-bit index (thread id <-> butterfly block)
__device__ __forceinline__ int rev3(int t){
    return ((t&7)<<6) | (t&56) | ((t>>6)&7);
}

// ---- 8-point DFT, inverse sign (sigma=+1). y_m = sum_k t_k w^{mk}, w=e^{+i pi/4}
__device__ __forceinline__ void dft8_inv(v2 t[8], v2 y[8]) {
    const float RH = 0.70710678f;
    v2 p  = t[0]+t[4], m  = t[0]-t[4], q  = t[2]+t[6], r  = t[2]-t[6];
    v2 rr = vrot(r);
    v2 E0 = p+q, E2 = p-q, E1 = m+rr, E3 = m-rr;
    v2 p2 = t[1]+t[5], m2 = t[1]-t[5], q2 = t[3]+t[7], r2 = t[3]-t[7];
    v2 rr2 = vrot(r2);
    v2 O0 = p2+q2, O2 = p2-q2, O1 = m2+rr2, O3 = m2-rr2;
    v2 W1O = RH*(O1 + vrot(O1));        // w^1 * O1
    v2 W2O = vrot(O2);                  // w^2 = i
    v2 W3O = vrot(RH*(O3 + vrot(O3)));  // w^3 = i*w
    y[0] = E0 + O0;  y[4] = E0 - O0;
    y[1] = E1 + W1O; y[5] = E1 - W1O;
    y[2] = E2 + W2O; y[6] = E2 - W2O;
    y[3] = E3 + W3O; y[7] = E3 - W3O;
}

// ---- 8-point DFT, forward sign (sigma=-1).
__device__ __forceinline__ void dft8_fwd(v2 t[8], v2 y[8]) {
    const float RH = 0.70710678f;
    v2 p  = t[0]+t[4], m  = t[0]-t[4], q  = t[2]+t[6], r  = t[2]-t[6];
    v2 rr = vrot(r);
    v2 E0 = p+q, E2 = p-q, E1 = m-rr, E3 = m+rr;
    v2 p2 = t[1]+t[5], m2 = t[1]-t[5], q2 = t[3]+t[7], r2 = t[3]-t[7];
    v2 rr2 = vrot(r2);
    v2 O0 = p2+q2, O2 = p2-q2, O1 = m2-rr2, O3 = m2+rr2;
    v2 W1O = RH*(O1 - vrot(O1));          // w = (1-i)/sqrt2
    v2 W2O = (v2){O2.y, -O2.x};           // w^2 = -i
    v2 W3O = (-RH)*(O3 + vrot(O3));       // w^3 = (-1-i)/sqrt2
    y[0] = E0 + O0;  y[4] = E0 - O0;
    y[1] = E1 + W1O; y[5] = E1 - W1O;
    y[2] = E2 + W2O; y[6] = E2 - W2O;
    y[3] = E3 + W3O; y[7] = E3 - W3O;
}

// ---- twiddle application for inverse DIT butterfly: t[k] *= W^k, W = e^{+2pi i j / (8Q)}
__device__ __forceinline__ void apply_tw_inv(v2 t[8], float fm, int j) {
    float sb, cb; __sincosf(fm*(float)j, &sb, &cb);
    v2 W1 = (v2){cb, sb};
    v2 W2 = vcmul(W1,W1), W3 = vcmul(W1,W2), W4 = vcmul(W2,W2),
       W5 = vcmul(W2,W3), W6 = vcmul(W3,W3), W7 = vcmul(W3,W4);
    t[1]=vcmul(t[1],W1); t[2]=vcmul(t[2],W2); t[3]=vcmul(t[3],W3);
    t[4]=vcmul(t[4],W4); t[5]=vcmul(t[5],W5); t[6]=vcmul(t[6],W6);
    t[7]=vcmul(t[7],W7);
}

// ---- radix-8 DIT pass, inverse, in-place over 4096 elems (standalone middle passes).
template<int Q>
__device__ __forceinline__ void r8_dit_inv(v2* buf, int tid) {
    int j = tid & (Q-1);
    int base = 8*tid - 7*j;
    v2 t[8];
    #pragma unroll
    for (int k = 0; k < 8; ++k) t[k] = buf[SW(base + k*Q)];
    apply_tw_inv(t, 6.2831853072f / (float)(8*Q), j);
    v2 y[8];
    dft8_inv(t, y);
    #pragma unroll
    for (int m = 0; m < 8; ++m) buf[SW(base + m*Q)] = y[m];
    __syncthreads();
}

// ---- radix-8 DIF pass, forward, applied to BOTH 4096-halves of buf.
template<int Q>
__device__ __forceinline__ void r8_dif_fwd(v2* buf, int tid) {
    int j = tid & (Q-1);
    int baseL = 8*tid - 7*j;
    v2 W1=(v2){1.0f,0.0f},W2=W1,W3=W1,W4=W1,W5=W1,W6=W1,W7=W1;
    if (Q > 1) {
        const float fm = -6.2831853072f / (float)(8*Q);
        float sb, cb; __sincosf(fm*(float)j, &sb, &cb);
        W1 = (v2){cb, sb};
        W2 = vcmul(W1,W1); W3 = vcmul(W1,W2); W4 = vcmul(W2,W2);
        W5 = vcmul(W2,W3); W6 = vcmul(W3,W3); W7 = vcmul(W3,W4);
    }
    #pragma unroll 1
    for (int hh = 0; hh < 2; ++hh) {
        int base = baseL + (hh << 12);
        v2 t[8];
        #pragma unroll
        for (int k = 0; k < 8; ++k) t[k] = buf[SW(base + k*Q)];
        v2 y[8];
        dft8_fwd(t, y);
        if (Q > 1) {
            y[1]=vcmul(y[1],W1); y[2]=vcmul(y[2],W2); y[3]=vcmul(y[3],W3);
            y[4]=vcmul(y[4],W4); y[5]=vcmul(y[5],W5); y[6]=vcmul(y[6],W6);
            y[7]=vcmul(y[7],W7);
        }
        #pragma unroll
        for (int m = 0; m < 8; ++m) buf[SW(base + m*Q)] = y[m];
    }
    __syncthreads();
}

// ---- prep kernel: per-(h,n) Cauchy weights -> workspace (wave-uniform s_load
// source for the main kernel's P1). ws8: 8 floats/entry, ws1: 1 float/entry.
__global__ void __launch_bounds__(64)
s4_prep(const float* __restrict__ Lre, const float* __restrict__ Lim,
        const float* __restrict__ Pre, const float* __restrict__ Pim,
        const float* __restrict__ Bre, const float* __restrict__ Bim,
        const float* __restrict__ Cin,
        float* __restrict__ ws8, float* __restrict__ ws1)
{
    int idx = blockIdx.x*64 + threadIdx.x;   // h*64 + n
    float lre = fminf(Lre[idx], -1e-4f);
    float lim = Lim[idx];
    float pr = Pre[idx], pi = Pim[idx];
    float br = Bre[idx], bi = Bim[idx];
    float cr = Cin[2*idx], ci = Cin[2*idx+1];
    v2 cc = (v2){cr, -ci};
    v2 w00 = vcmul(cc, (v2){br, bi});     // conj(C)*B
    v2 w01 = vcmul(cc, (v2){pr, pi});     // conj(C)*P
    v2 w10 = vcmul((v2){pr,-pi}, (v2){br, bi});  // conj(P)*B
    float* o = ws8 + idx*8;
    o[0] = -lre;  o[1] = -lim;
    o[2] = w00.x; o[3] = w00.y;
    o[4] = w01.x; o[5] = w01.y;
    o[6] = w10.x; o[7] = w10.y;
    ws1[idx] = pr*pr + pi*pi;             // |P|^2 (real weight of k11)
}

// Fused S4 layer, one block per channel h. Structure as R8 (8 standalone LDS
// passes, first/last FFT passes fused into producer/consumer phases).
// P1 uses the analytic form: g = i*t, t = -(2/step)*tan(ang/2);
// c = 2/(1+Omega) = (1, t*step/2). No f64 sincos, no LDS param reads.
__global__ void __launch_bounds__(NT)
s4_fused(const float* __restrict__ u,
         const float* __restrict__ Din, const float* __restrict__ logstep,
         const float* __restrict__ ws8, const float* __restrict__ ws1,
         float* __restrict__ out)
{
    __shared__ v2 buf[8192];   // 64 KB -> 2 blocks/CU
    const int tid = threadIdx.x;
    const int h = blockIdx.x;

    const float step = expf(logstep[h]);
    const float tos  = 2.0f / step;
    const float hstep = 0.5f * step;
    const float* pp = ws8 + (h*64)*8;   // wave-uniform -> s_load
    const float* pw = ws1 + h*64;

    // ---- P1: Cauchy kernel; hp0's 4 results staged raw in LDS, hp1's kept in
    //      regs; then the P2 Q=1 butterfly runs in registers. ----
    v2 a4[4];
    #pragma unroll 1
    for (int hp = 0; hp < 2; ++hp) {
        float tv[4];
        v2 cf[4], k00[4], k01[4], k10[4], k11[4];
        const int lbase = hp*(4*NT);
        #pragma unroll
        for (int i = 0; i < 4; ++i) {
            int l = lbase + i*NT + tid;
            // reference's f32 angle; g = i*t with t = -tos*tan(ang/2) (exact identity:
            // (1-e^{i ang})/(1+e^{i ang}) = -i tan(ang/2); removes the 1-|Omega|^2
            // cancellation and the need for f64 sincos)
            float ang = -6.2831855f * ((float)l * (1.0f/4096.0f));
            float sh, ch; __sincosf(0.5f*ang, &sh, &ch);
            float traw = -tos * sh * __builtin_amdgcn_rcpf(ch);
            float t = fminf(fmaxf(traw, -1e18f), 1e18f);   // guard cos==0 -> inf*0 NaN
            tv[i] = t;
            cf[i] = (v2){1.0f, t*hstep};                   // c = 1 - i*tan(ang/2)
            k00[i]=(v2)(0.0f); k01[i]=(v2)(0.0f); k10[i]=(v2)(0.0f); k11[i]=(v2)(0.0f);
        }
        #pragma unroll 1
        for (int n = 0; n < 64; ++n) {
            float nlre = pp[n*8+0], nlim = pp[n*8+1];      // = -lre, -lim (scalar pipe)
            v2 w00 = (v2){pp[n*8+2], pp[n*8+3]};
            v2 w01 = (v2){pp[n*8+4], pp[n*8+5]};
            v2 w10 = (v2){pp[n*8+6], pp[n*8+7]};
            float w11r = pw[n];
            float lre2 = nlre*nlre;
            #pragma unroll
            for (int i = 0; i < 4; ++i) {
                float s = tv[i] + nlim;                    // t - lim
                float inv = __builtin_amdgcn_rcpf(__builtin_fmaf(s, s, lre2));
                v2 p = (v2){nlre, s} * inv;                // d*inv, d = g - lam = (-lre, t-lim)
                v2 cp = (v2){p.x, -p.y};                   // 1/(g-lam)
                v2 rp = (v2){p.y,  p.x};
                k00[i] = vfma1(w00.y, rp, vfma1(w00.x, cp, k00[i]));
                k01[i] = vfma1(w01.y, rp, vfma1(w01.x, cp, k01[i]));
                k10[i] = vfma1(w10.y, rp, vfma1(w10.x, cp, k10[i]));
                k11[i] = vfma1(w11r,  cp, k11[i]);
            }
        }
        #pragma unroll
        for (int i = 0; i < 4; ++i) {
            v2 opk = (v2){1.0f + k11[i].x, k11[i].y};
            float iv = __builtin_amdgcn_rcpf(opk.x*opk.x + opk.y*opk.y);
            v2 r11 = vconj(opk) * iv;
            v2 t  = vcmul(vcmul(k01[i], r11), k10[i]);
            v2 res = vcmul(cf[i], k00[i] - t);             // atRoots[l], l = tid+512*(4hp+i)
            if (hp == 0) buf[SW(tid + 512*i)] = res;       // stage raw
            else         a4[i] = res;
        }
    }
    {   // fused P2 Q=1 butterfly: t[k] = atRoots[tid + 512k]
        v2 t[8];
        #pragma unroll
        for (int k = 0; k < 4; ++k) t[k] = buf[SW(tid + 512*k)];   // own raw stage
        #pragma unroll
        for (int k = 0; k < 4; ++k) t[4+k] = a4[k];
        __syncthreads();                    // all raw reads done before any butterfly write
        v2 y[8];
        dft8_inv(t, y);
        int tb8 = 8*rev3(tid);
        #pragma unroll
        for (int m = 0; m < 8; ++m) buf[SW(tb8 + m)] = y[m];
    }
    __syncthreads();

    // ---- P2: ifft4096 middle passes ----
    r8_dit_inv<8 >(buf, tid);
    r8_dit_inv<64>(buf, tid);

    // ---- P3: fused P2-Q512 butterfly + pack z = u + i*K + r2 stage of fft8192
    //      (upper input is the zero pad: buf[l]=z, buf[l+4096]=z*W_8192^{-l}). ----
    {
        v2 t[8];
        #pragma unroll
        for (int k = 0; k < 8; ++k) t[k] = buf[SW(tid + 512*k)];
        apply_tw_inv(t, 6.2831853072f / 4096.0f, tid);
        v2 y[8];
        dft8_inv(t, y);                          // y[m] = K*4096 at l = tid+512m
        float uval[8];
        const float* up = u + h*4096;
        #pragma unroll
        for (int m = 0; m < 8; ++m) uval[m] = up[tid + 512*m];
        __syncthreads();                         // all Q512 reads done before pack writes
        float s2, c2; __sincosf(-6.2831853072f/8192.0f*(float)tid, &s2, &c2);
        v2 cur = (v2){c2, s2};                   // W_8192^{-tid}
        const v2 C16n = (v2){0.92387953f, -0.38268343f};   // e^{-i pi/8} = W_8192^{-512}
        #pragma unroll
        for (int m = 0; m < 8; ++m) {
            int l = tid + 512*m;
            v2 z = (v2){uval[m], y[m].x * (1.0f/4096.0f)};
            buf[SW(l)]      = z;
            buf[SW(l+4096)] = vcmul(z, cur);
            cur = vcmul(cur, C16n);
        }
    }
    __syncthreads();

    // ---- P4: forward fft8192 remaining stages (r2 folded into P3).
    //      Z[k] lands at ((k&1)<<12) + d8r4(k>>1).
    r8_dif_fwd<512>(buf, tid);
    r8_dif_fwd<64 >(buf, tid);
    r8_dif_fwd<8  >(buf, tid);
    r8_dif_fwd<1  >(buf, tid);

    // ---- P5: unpack + multiply + half-size-inverse pack, fused with P6 Q=1
    //      butterfly (v[i] for r = tid+512i are exactly block 8*rev3(tid)'s inputs).
    {
        float sb, cb; __sincosf(6.2831853072f/8192.0f*(float)tid, &sb, &cb);
        v2 cur = (v2){cb, sb};                   // W_8192^{+tid}
        const v2 C16p = (v2){0.92387953f, 0.38268343f};    // e^{+i pi/8}
        v2 v[8];
        #pragma unroll 1
        for (int i = 0; i < 8; ++i) {
            int r  = i*NT + tid;                 // 0..4095
            int k1 = r,        k1c = (8192 - r) & 8191;
            int k2 = r + 4096, k2c = 4096 - r;
            v2 za = buf[SW(((k1 &1)<<12) + d8r4(k1 >>1))];
            v2 zb = buf[SW(((k1c&1)<<12) + d8r4(k1c>>1))];
            v2 zc = buf[SW(((k2 &1)<<12) + d8r4(k2 >>1))];
            v2 zd = buf[SW(((k2c&1)<<12) + d8r4(k2c>>1))];
            v2 U1 = 0.5f*(za + vconj(zb));
            v2 K1 = -0.5f*vrot(za - vconj(zb));
            v2 Yr = vcmul(U1, K1);                               // Y[r]
            v2 U2 = 0.5f*(zc + vconj(zd));
            v2 K2 = -0.5f*vrot(zc - vconj(zd));
            v2 Ys = vcmul(U2, K2);                               // Y[r+4096]
            v[i] = (Yr + Ys) + vrot(vcmul(cur, Yr - Ys));        // A + i*W^r*(Yr-Ys)
            cur = vcmul(cur, C16p);
        }
        __syncthreads();                         // all gathers done before butterfly writes
        v2 y[8];
        dft8_inv(v, y);
        int tb8 = 8*rev3(tid);
        #pragma unroll
        for (int m = 0; m < 8; ++m) buf[SW(tb8 + m)] = y[m];
    }
    __syncthreads();

    // ---- P6: ifft4096 middle passes ----
    r8_dit_inv<8 >(buf, tid);
    r8_dit_inv<64>(buf, tid);

    // ---- P7: fused P6-Q512 butterfly + epilogue. Only m<4 (first 4096 reals)
    //      survive the causal-conv truncation. ----
    {
        v2 t[8];
        #pragma unroll
        for (int k = 0; k < 8; ++k) t[k] = buf[SW(tid + 512*k)];
        apply_tw_inv(t, 6.2831853072f / 4096.0f, tid);
        v2 y[8];
        dft8_inv(t, y);
        const float Dh = Din[h];
        const float sc = 1.0f / 8192.0f;
        const v2* u2 = (const v2*)(u + h*4096);
        v2*     out2 = (v2*)(out + h*4096);
        #pragma unroll
        for (int m = 0; m < 4; ++m) {
            int n = tid + 512*m;                 // v2-pair index -> outputs 2n, 2n+1
            out2[n] = sc*y[m] + Dh*u2[n];
        }
    }
}

extern "C" void kernel_launch(void* const* d_in, const int* in_sizes, int n_in,
                              void* d_out, int out_size, void* d_ws, size_t ws_size,
                              hipStream_t stream)
{
    const float* u       = (const float*)d_in[0];
    const float* Lre     = (const float*)d_in[1];
    const float* Lim     = (const float*)d_in[2];
    const float* Pre     = (const float*)d_in[3];
    const float* Pim     = (const float*)d_in[4];
    const float* Bre     = (const float*)d_in[5];
    const float* Bim     = (const float*)d_in[6];
    const float* Cin     = (const float*)d_in[7];
    const float* Din     = (const float*)d_in[8];
    const float* logstep = (const float*)d_in[9];
    float* out = (float*)d_out;
    const int H = in_sizes[8];  // D is [H,1]

    float* ws8 = (float*)d_ws;            // H*64*8 floats
    float* ws1 = ws8 + (size_t)H*64*8;    // H*64 floats  (total ~1.13 MB << ws_size)

    hipLaunchKernelGGL(s4_prep, dim3(H), dim3(64), 0, stream,
                       Lre, Lim, Pre, Pim, Bre, Bim, Cin, ws8, ws1);
    hipLaunchKernelGGL(s4_fused, dim3(H), dim3(NT), 0, stream,
                       u, Din, logstep, ws8, ws1, out);
}

// Round 12
// 162.404 us; speedup vs baseline: 1.0584x; 1.0584x over previous
//
#include <hip/hip_runtime.h>
#include <math.h>

#define NT 512   // threads per block; 512 blocks (one per channel h)

// Packed f32 pair: LLVM lowers arithmetic on this to v_pk_*_f32 (VOP3P) on gfx950.
typedef float v2 __attribute__((ext_vector_type(2)));

__device__ __forceinline__ v2 vrot(v2 a){ return (v2){-a.y, a.x}; }            // i*a
__device__ __forceinline__ v2 vconj(v2 a){ return (v2){a.x, -a.y}; }
__device__ __forceinline__ v2 vcmul(v2 a, v2 b){ return a.x*b + a.y*vrot(b); } // complex mul: 2 pk_fma
__device__ __forceinline__ v2 vfma1(float s, v2 v, v2 acc){                    // acc + s*v: 1 pk_fma
    return (v2){ __builtin_fmaf(s, v.x, acc.x), __builtin_fmaf(s, v.y, acc.y) };
}

// XOR bank swizzle: float2 elements -> bank = (2e)%32 depends on e mod 16.
__device__ __forceinline__ int SW(int e){ return e ^ (((e>>5) ^ (e>>9)) & 15); }

// base-8 digit reversal of a 12-bit index
__device__ __forceinline__ int d8r4(int x){
    return ((x&7)<<9) | (((x>>3)&7)<<6) | (((x>>6)&7)<<3) | ((x>>9)&7);
}
// base-8 digit reversal of a 9-bit index (thread id <-> butterfly block)
__device__ __forceinline__ int rev3(int t){
    return ((t&7)<<6) | (t&56) | ((t>>6)&7);
}

// ---- 8-point DFT, inverse sign (sigma=+1). y_m = sum_k t_k w^{mk}, w=e^{+i pi/4}
__device__ __forceinline__ void dft8_inv(v2 t[8], v2 y[8]) {
    const float RH = 0.70710678f;
    v2 p  = t[0]+t[4], m  = t[0]-t[4], q  = t[2]+t[6], r  = t[2]-t[6];
    v2 rr = vrot(r);
    v2 E0 = p+q, E2 = p-q, E1 = m+rr, E3 = m-rr;
    v2 p2 = t[1]+t[5], m2 = t[1]-t[5], q2 = t[3]+t[7], r2 = t[3]-t[7];
    v2 rr2 = vrot(r2);
    v2 O0 = p2+q2, O2 = p2-q2, O1 = m2+rr2, O3 = m2-rr2;
    v2 W1O = RH*(O1 + vrot(O1));        // w^1 * O1
    v2 W2O = vrot(O2);                  // w^2 = i
    v2 W3O = vrot(RH*(O3 + vrot(O3)));  // w^3 = i*w
    y[0] = E0 + O0;  y[4] = E0 - O0;
    y[1] = E1 + W1O; y[5] = E1 - W1O;
    y[2] = E2 + W2O; y[6] = E2 - W2O;
    y[3] = E3 + W3O; y[7] = E3 - W3O;
}

// ---- 8-point DFT, forward sign (sigma=-1).
__device__ __forceinline__ void dft8_fwd(v2 t[8], v2 y[8]) {
    const float RH = 0.70710678f;
    v2 p  = t[0]+t[4], m  = t[0]-t[4], q  = t[2]+t[6], r  = t[2]-t[6];
    v2 rr = vrot(r);
    v2 E0 = p+q, E2 = p-q, E1 = m-rr, E3 = m+rr;
    v2 p2 = t[1]+t[5], m2 = t[1]-t[5], q2 = t[3]+t[7], r2 = t[3]-t[7];
    v2 rr2 = vrot(r2);
    v2 O0 = p2+q2, O2 = p2-q2, O1 = m2-rr2, O3 = m2+rr2;
    v2 W1O = RH*(O1 - vrot(O1));          // w = (1-i)/sqrt2
    v2 W2O = (v2){O2.y, -O2.x};           // w^2 = -i
    v2 W3O = (-RH)*(O3 + vrot(O3));       // w^3 = (-1-i)/sqrt2
    y[0] = E0 + O0;  y[4] = E0 - O0;
    y[1] = E1 + W1O; y[5] = E1 - W1O;
    y[2] = E2 + W2O; y[6] = E2 - W2O;
    y[3] = E3 + W3O; y[7] = E3 - W3O;
}

// ---- twiddle application for inverse DIT butterfly: t[k] *= W^k, W = e^{+2pi i j / (8Q)}
__device__ __forceinline__ void apply_tw_inv(v2 t[8], float fm, int j) {
    float sb, cb; __sincosf(fm*(float)j, &sb, &cb);
    v2 W1 = (v2){cb, sb};
    v2 W2 = vcmul(W1,W1), W3 = vcmul(W1,W2), W4 = vcmul(W2,W2),
       W5 = vcmul(W2,W3), W6 = vcmul(W3,W3), W7 = vcmul(W3,W4);
    t[1]=vcmul(t[1],W1); t[2]=vcmul(t[2],W2); t[3]=vcmul(t[3],W3);
    t[4]=vcmul(t[4],W4); t[5]=vcmul(t[5],W5); t[6]=vcmul(t[6],W6);
    t[7]=vcmul(t[7],W7);
}

// ---- radix-8 DIT pass, inverse, in-place over 4096 elems (standalone middle passes).
template<int Q>
__device__ __forceinline__ void r8_dit_inv(v2* buf, int tid) {
    int j = tid & (Q-1);
    int base = 8*tid - 7*j;
    v2 t[8];
    #pragma unroll
    for (int k = 0; k < 8; ++k) t[k] = buf[SW(base + k*Q)];
    apply_tw_inv(t, 6.2831853072f / (float)(8*Q), j);
    v2 y[8];
    dft8_inv(t, y);
    #pragma unroll
    for (int m = 0; m < 8; ++m) buf[SW(base + m*Q)] = y[m];
    __syncthreads();
}

// ---- radix-8 DIF pass, forward, applied to BOTH 4096-halves of buf.
template<int Q>
__device__ __forceinline__ void r8_dif_fwd(v2* buf, int tid) {
    int j = tid & (Q-1);
    int baseL = 8*tid - 7*j;
    v2 W1=(v2){1.0f,0.0f},W2=W1,W3=W1,W4=W1,W5=W1,W6=W1,W7=W1;
    if (Q > 1) {
        const float fm = -6.2831853072f / (float)(8*Q);
        float sb, cb; __sincosf(fm*(float)j, &sb, &cb);
        W1 = (v2){cb, sb};
        W2 = vcmul(W1,W1); W3 = vcmul(W1,W2); W4 = vcmul(W2,W2);
        W5 = vcmul(W2,W3); W6 = vcmul(W3,W3); W7 = vcmul(W3,W4);
    }
    #pragma unroll 1
    for (int hh = 0; hh < 2; ++hh) {
        int base = baseL + (hh << 12);
        v2 t[8];
        #pragma unroll
        for (int k = 0; k < 8; ++k) t[k] = buf[SW(base + k*Q)];
        v2 y[8];
        dft8_fwd(t, y);
        if (Q > 1) {
            y[1]=vcmul(y[1],W1); y[2]=vcmul(y[2],W2); y[3]=vcmul(y[3],W3);
            y[4]=vcmul(y[4],W4); y[5]=vcmul(y[5],W5); y[6]=vcmul(y[6],W6);
            y[7]=vcmul(y[7],W7);
        }
        #pragma unroll
        for (int m = 0; m < 8; ++m) buf[SW(base + m*Q)] = y[m];
    }
    __syncthreads();
}

// ---- prep kernel: per-(h,n) Cauchy weights -> workspace (wave-uniform s_load
// source for the main kernel's P1). ws8: 8 floats/entry, ws1: 1 float/entry.
__global__ void __launch_bounds__(64)
s4_prep(const float* __restrict__ Lre, const float* __restrict__ Lim,
        const float* __restrict__ Pre, const float* __restrict__ Pim,
        const float* __restrict__ Bre, const float* __restrict__ Bim,
        const float* __restrict__ Cin,
        float* __restrict__ ws8, float* __restrict__ ws1)
{
    int idx = blockIdx.x*64 + threadIdx.x;   // h*64 + n
    float lre = fminf(Lre[idx], -1e-4f);
    float lim = Lim[idx];
    float pr = Pre[idx], pi = Pim[idx];
    float br = Bre[idx], bi = Bim[idx];
    float cr = Cin[2*idx], ci = Cin[2*idx+1];
    v2 cc = (v2){cr, -ci};
    v2 w00 = vcmul(cc, (v2){br, bi});     // conj(C)*B
    v2 w01 = vcmul(cc, (v2){pr, pi});     // conj(C)*P
    v2 w10 = vcmul((v2){pr,-pi}, (v2){br, bi});  // conj(P)*B
    float* o = ws8 + idx*8;
    o[0] = -lre;  o[1] = -lim;
    o[2] = w00.x; o[3] = w00.y;
    o[4] = w01.x; o[5] = w01.y;
    o[6] = w10.x; o[7] = w10.y;
    ws1[idx] = pr*pr + pi*pi;             // |P|^2 (real weight of k11)
}

// Fused S4 layer, one block per channel h. R9 structure (8 standalone LDS
// passes, first/last FFT passes fused into producer/consumer phases; analytic
// g = i*t, scalar-pipe param loads). NOTE (R10 post-mortem): atRoots is NOT
// Hermitian (random C breaks conjugate pairing); the reference's .real imposes
// the symmetry by averaging both halves -- both halves must be computed.
// R11 lever: n-loop unroll 4 batches s_load_dwordx8's to hide scalar latency.
__global__ void __launch_bounds__(NT)
s4_fused(const float* __restrict__ u,
         const float* __restrict__ Din, const float* __restrict__ logstep,
         const float* __restrict__ ws8, const float* __restrict__ ws1,
         float* __restrict__ out)
{
    __shared__ v2 buf[8192];   // 64 KB -> 2 blocks/CU
    const int tid = threadIdx.x;
    const int h = blockIdx.x;

    const float step = expf(logstep[h]);
    const float tos  = 2.0f / step;
    const float hstep = 0.5f * step;
    const float* pp = ws8 + (h*64)*8;   // wave-uniform -> s_load
    const float* pw = ws1 + h*64;

    // ---- P1: Cauchy kernel; hp0's 4 results staged raw in LDS, hp1's kept in
    //      regs; then the P2 Q=1 butterfly runs in registers. ----
    v2 a4[4];
    #pragma unroll 1
    for (int hp = 0; hp < 2; ++hp) {
        float tv[4];
        v2 cf[4], k00[4], k01[4], k10[4], k11[4];
        const int lbase = hp*(4*NT);
        #pragma unroll
        for (int i = 0; i < 4; ++i) {
            int l = lbase + i*NT + tid;
            // reference's f32 angle; g = i*t with t = -tos*tan(ang/2) (exact identity:
            // (1-e^{i ang})/(1+e^{i ang}) = -i tan(ang/2))
            float ang = -6.2831855f * ((float)l * (1.0f/4096.0f));
            float sh, ch; __sincosf(0.5f*ang, &sh, &ch);
            float traw = -tos * sh * __builtin_amdgcn_rcpf(ch);
            float t = fminf(fmaxf(traw, -1e18f), 1e18f);   // guard cos==0 -> inf*0 NaN
            tv[i] = t;
            cf[i] = (v2){1.0f, t*hstep};                   // c = 1 - i*tan(ang/2)
            k00[i]=(v2)(0.0f); k01[i]=(v2)(0.0f); k10[i]=(v2)(0.0f); k11[i]=(v2)(0.0f);
        }
        #pragma unroll 4
        for (int n = 0; n < 64; ++n) {
            float nlre = pp[n*8+0], nlim = pp[n*8+1];      // scalar pipe (s_load_dwordx8)
            v2 w00 = (v2){pp[n*8+2], pp[n*8+3]};
            v2 w01 = (v2){pp[n*8+4], pp[n*8+5]};
            v2 w10 = (v2){pp[n*8+6], pp[n*8+7]};
            float w11r = pw[n];
            float lre2 = nlre*nlre;
            #pragma unroll
            for (int i = 0; i < 4; ++i) {
                float s = tv[i] + nlim;                    // t - lim
                float inv = __builtin_amdgcn_rcpf(__builtin_fmaf(s, s, lre2));
                v2 p = (v2){nlre, s} * inv;                // d*inv, d = g - lam = (-lre, t-lim)
                v2 cp = (v2){p.x, -p.y};                   // 1/(g-lam)
                v2 rp = (v2){p.y,  p.x};
                k00[i] = vfma1(w00.y, rp, vfma1(w00.x, cp, k00[i]));
                k01[i] = vfma1(w01.y, rp, vfma1(w01.x, cp, k01[i]));
                k10[i] = vfma1(w10.y, rp, vfma1(w10.x, cp, k10[i]));
                k11[i] = vfma1(w11r,  cp, k11[i]);
            }
        }
        #pragma unroll
        for (int i = 0; i < 4; ++i) {
            v2 opk = (v2){1.0f + k11[i].x, k11[i].y};
            float iv = __builtin_amdgcn_rcpf(opk.x*opk.x + opk.y*opk.y);
            v2 r11 = vconj(opk) * iv;
            v2 t  = vcmul(vcmul(k01[i], r11), k10[i]);
            v2 res = vcmul(cf[i], k00[i] - t);             // atRoots[l], l = tid+512*(4hp+i)
            if (hp == 0) buf[SW(tid + 512*i)] = res;       // stage raw
            else         a4[i] = res;
        }
    }
    {   // fused P2 Q=1 butterfly: t[k] = atRoots[tid + 512k]
        v2 t[8];
        #pragma unroll
        for (int k = 0; k < 4; ++k) t[k] = buf[SW(tid + 512*k)];   // own raw stage
        #pragma unroll
        for (int k = 0; k < 4; ++k) t[4+k] = a4[k];
        __syncthreads();                    // all raw reads done before any butterfly write
        v2 y[8];
        dft8_inv(t, y);
        int tb8 = 8*rev3(tid);
        #pragma unroll
        for (int m = 0; m < 8; ++m) buf[SW(tb8 + m)] = y[m];
    }
    __syncthreads();

    // ---- P2: ifft4096 middle passes ----
    r8_dit_inv<8 >(buf, tid);
    r8_dit_inv<64>(buf, tid);

    // ---- P3: fused P2-Q512 butterfly + pack z = u + i*K + r2 stage of fft8192
    //      (upper input is the zero pad: buf[l]=z, buf[l+4096]=z*W_8192^{-l}). ----
    {
        v2 t[8];
        #pragma unroll
        for (int k = 0; k < 8; ++k) t[k] = buf[SW(tid + 512*k)];
        apply_tw_inv(t, 6.2831853072f / 4096.0f, tid);
        v2 y[8];
        dft8_inv(t, y);                          // y[m] = K*4096 at l = tid+512m
        float uval[8];
        const float* up = u + h*4096;
        #pragma unroll
        for (int m = 0; m < 8; ++m) uval[m] = up[tid + 512*m];
        __syncthreads();                         // all Q512 reads done before pack writes
        float s2, c2; __sincosf(-6.2831853072f/8192.0f*(float)tid, &s2, &c2);
        v2 cur = (v2){c2, s2};                   // W_8192^{-tid}
        const v2 C16n = (v2){0.92387953f, -0.38268343f};   // e^{-i pi/8} = W_8192^{-512}
        #pragma unroll
        for (int m = 0; m < 8; ++m) {
            int l = tid + 512*m;
            v2 z = (v2){uval[m], y[m].x * (1.0f/4096.0f)};
            buf[SW(l)]      = z;
            buf[SW(l+4096)] = vcmul(z, cur);
            cur = vcmul(cur, C16n);
        }
    }
    __syncthreads();

    // ---- P4: forward fft8192 remaining stages (r2 folded into P3).
    //      Z[k] lands at ((k&1)<<12) + d8r4(k>>1).
    r8_dif_fwd<512>(buf, tid);
    r8_dif_fwd<64 >(buf, tid);
    r8_dif_fwd<8  >(buf, tid);
    r8_dif_fwd<1  >(buf, tid);

    // ---- P5: unpack + multiply + half-size-inverse pack, fused with P6 Q=1
    //      butterfly (v[i] for r = tid+512i are exactly block 8*rev3(tid)'s inputs).
    {
        float sb, cb; __sincosf(6.2831853072f/8192.0f*(float)tid, &sb, &cb);
        v2 cur = (v2){cb, sb};                   // W_8192^{+tid}
        const v2 C16p = (v2){0.92387953f, 0.38268343f};    // e^{+i pi/8}
        v2 v[8];
        #pragma unroll 1
        for (int i = 0; i < 8; ++i) {
            int r  = i*NT + tid;                 // 0..4095
            int k1 = r,        k1c = (8192 - r) & 8191;
            int k2 = r + 4096, k2c = 4096 - r;
            v2 za = buf[SW(((k1 &1)<<12) + d8r4(k1 >>1))];
            v2 zb = buf[SW(((k1c&1)<<12) + d8r4(k1c>>1))];
            v2 zc = buf[SW(((k2 &1)<<12) + d8r4(k2 >>1))];
            v2 zd = buf[SW(((k2c&1)<<12) + d8r4(k2c>>1))];
            v2 U1 = 0.5f*(za + vconj(zb));
            v2 K1 = -0.5f*vrot(za - vconj(zb));
            v2 Yr = vcmul(U1, K1);                               // Y[r]
            v2 U2 = 0.5f*(zc + vconj(zd));
            v2 K2 = -0.5f*vrot(zc - vconj(zd));
            v2 Ys = vcmul(U2, K2);                               // Y[r+4096]
            v[i] = (Yr + Ys) + vrot(vcmul(cur, Yr - Ys));        // A + i*W^r*(Yr-Ys)
            cur = vcmul(cur, C16p);
        }
        __syncthreads();                         // all gathers done before butterfly writes
        v2 y[8];
        dft8_inv(v, y);
        int tb8 = 8*rev3(tid);
        #pragma unroll
        for (int m = 0; m < 8; ++m) buf[SW(tb8 + m)] = y[m];
    }
    __syncthreads();

    // ---- P6: ifft4096 middle passes ----
    r8_dit_inv<8 >(buf, tid);
    r8_dit_inv<64>(buf, tid);

    // ---- P7: fused P6-Q512 butterfly + epilogue. Only m<4 (first 4096 reals)
    //      survive the causal-conv truncation. ----
    {
        v2 t[8];
        #pragma unroll
        for (int k = 0; k < 8; ++k) t[k] = buf[SW(tid + 512*k)];
        apply_tw_inv(t, 6.2831853072f / 4096.0f, tid);
        v2 y[8];
        dft8_inv(t, y);
        const float Dh = Din[h];
        const float sc = 1.0f / 8192.0f;
        const v2* u2 = (const v2*)(u + h*4096);
        v2*     out2 = (v2*)(out + h*4096);
        #pragma unroll
        for (int m = 0; m < 4; ++m) {
            int n = tid + 512*m;                 // v2-pair index -> outputs 2n, 2n+1
            out2[n] = sc*y[m] + Dh*u2[n];
        }
    }
}

extern "C" void kernel_launch(void* const* d_in, const int* in_sizes, int n_in,
                              void* d_out, int out_size, void* d_ws, size_t ws_size,
                              hipStream_t stream)
{
    const float* u       = (const float*)d_in[0];
    const float* Lre     = (const float*)d_in[1];
    const float* Lim     = (const float*)d_in[2];
    const float* Pre     = (const float*)d_in[3];
    const float* Pim     = (const float*)d_in[4];
    const float* Bre     = (const float*)d_in[5];
    const float* Bim     = (const float*)d_in[6];
    const float* Cin     = (const float*)d_in[7];
    const float* Din     = (const float*)d_in[8];
    const float* logstep = (const float*)d_in[9];
    float* out = (float*)d_out;
    const int H = in_sizes[8];  // D is [H,1]

    float* ws8 = (float*)d_ws;            // H*64*8 floats
    float* ws1 = ws8 + (size_t)H*64*8;    // H*64 floats  (total ~1.13 MB << ws_size)

    hipLaunchKernelGGL(s4_prep, dim3(H), dim3(64), 0, stream,
                       Lre, Lim, Pre, Pim, Bre, Bim, Cin, ws8, ws1);
    hipLaunchKernelGGL(s4_fused, dim3(H), dim3(NT), 0, stream,
                       u, Din, logstep, ws8, ws1, out);
}

// Round 13
// 159.748 us; speedup vs baseline: 1.0760x; 1.0166x over previous
//
#include <hip/hip_runtime.h>
#include <math.h>

#define NT 512   // threads per block; 512 blocks (one per channel h)

// Packed f32 pair: LLVM lowers arithmetic on this to v_pk_*_f32 (VOP3P) on gfx950.
typedef float v2 __attribute__((ext_vector_type(2)));

__device__ __forceinline__ v2 vrot(v2 a){ return (v2){-a.y, a.x}; }            // i*a
__device__ __forceinline__ v2 vconj(v2 a){ return (v2){a.x, -a.y}; }
__device__ __forceinline__ v2 vcmul(v2 a, v2 b){ return a.x*b + a.y*vrot(b); } // complex mul: 2 pk_fma
__device__ __forceinline__ v2 vfma1(float s, v2 v, v2 acc){                    // acc + s*v: 1 pk_fma
    return (v2){ __builtin_fmaf(s, v.x, acc.x), __builtin_fmaf(s, v.y, acc.y) };
}

// XOR bank swizzle: float2 elements -> bank = (2e)%32 depends on e mod 16.
// NOTE: SW changes bits 0-3 only => every address stays inside its aligned
// 512-element region (the wave-ownership argument below relies on this).
__device__ __forceinline__ int SW(int e){ return e ^ (((e>>5) ^ (e>>9)) & 15); }

// base-8 digit reversal of a 12-bit index
__device__ __forceinline__ int d8r4(int x){
    return ((x&7)<<9) | (((x>>3)&7)<<6) | (((x>>6)&7)<<3) | ((x>>9)&7);
}
// base-8 digit reversal of a 9-bit index (thread id <-> butterfly block)
__device__ __forceinline__ int rev3(int t){
    return ((t&7)<<6) | (t&56) | ((t>>6)&7);
}

// ---- 8-point DFT, inverse sign (sigma=+1). y_m = sum_k t_k w^{mk}, w=e^{+i pi/4}
__device__ __forceinline__ void dft8_inv(v2 t[8], v2 y[8]) {
    const float RH = 0.70710678f;
    v2 p  = t[0]+t[4], m  = t[0]-t[4], q  = t[2]+t[6], r  = t[2]-t[6];
    v2 rr = vrot(r);
    v2 E0 = p+q, E2 = p-q, E1 = m+rr, E3 = m-rr;
    v2 p2 = t[1]+t[5], m2 = t[1]-t[5], q2 = t[3]+t[7], r2 = t[3]-t[7];
    v2 rr2 = vrot(r2);
    v2 O0 = p2+q2, O2 = p2-q2, O1 = m2+rr2, O3 = m2-rr2;
    v2 W1O = RH*(O1 + vrot(O1));        // w^1 * O1
    v2 W2O = vrot(O2);                  // w^2 = i
    v2 W3O = vrot(RH*(O3 + vrot(O3)));  // w^3 = i*w
    y[0] = E0 + O0;  y[4] = E0 - O0;
    y[1] = E1 + W1O; y[5] = E1 - W1O;
    y[2] = E2 + W2O; y[6] = E2 - W2O;
    y[3] = E3 + W3O; y[7] = E3 - W3O;
}

// ---- 8-point DFT, forward sign (sigma=-1).
__device__ __forceinline__ void dft8_fwd(v2 t[8], v2 y[8]) {
    const float RH = 0.70710678f;
    v2 p  = t[0]+t[4], m  = t[0]-t[4], q  = t[2]+t[6], r  = t[2]-t[6];
    v2 rr = vrot(r);
    v2 E0 = p+q, E2 = p-q, E1 = m-rr, E3 = m+rr;
    v2 p2 = t[1]+t[5], m2 = t[1]-t[5], q2 = t[3]+t[7], r2 = t[3]-t[7];
    v2 rr2 = vrot(r2);
    v2 O0 = p2+q2, O2 = p2-q2, O1 = m2-rr2, O3 = m2+rr2;
    v2 W1O = RH*(O1 - vrot(O1));          // w = (1-i)/sqrt2
    v2 W2O = (v2){O2.y, -O2.x};           // w^2 = -i
    v2 W3O = (-RH)*(O3 + vrot(O3));       // w^3 = (-1-i)/sqrt2
    y[0] = E0 + O0;  y[4] = E0 - O0;
    y[1] = E1 + W1O; y[5] = E1 - W1O;
    y[2] = E2 + W2O; y[6] = E2 - W2O;
    y[3] = E3 + W3O; y[7] = E3 - W3O;
}

// ---- twiddle application for inverse DIT butterfly: t[k] *= W^k, W = e^{+2pi i j / (8Q)}
__device__ __forceinline__ void apply_tw_inv(v2 t[8], float fm, int j) {
    float sb, cb; __sincosf(fm*(float)j, &sb, &cb);
    v2 W1 = (v2){cb, sb};
    v2 W2 = vcmul(W1,W1), W3 = vcmul(W1,W2), W4 = vcmul(W2,W2),
       W5 = vcmul(W2,W3), W6 = vcmul(W3,W3), W7 = vcmul(W3,W4);
    t[1]=vcmul(t[1],W1); t[2]=vcmul(t[2],W2); t[3]=vcmul(t[3],W3);
    t[4]=vcmul(t[4],W4); t[5]=vcmul(t[5],W5); t[6]=vcmul(t[6],W6);
    t[7]=vcmul(t[7],W7);
}

// Wave-locality: for Q in {1,8,64}, thread t's butterfly addresses lie in the
// aligned 512-elem region [512*(t>>6), +512), owned exclusively by t's wave
// (64 threads). LDS ops within a wave execute in issue order, so consecutive
// wave-local passes need only a compiler fence, not __syncthreads.
// BAR=true emits the block barrier (needed when the NEXT consumer crosses waves).

// ---- radix-8 DIT pass, inverse, in-place over 4096 elems.
template<int Q, bool BAR>
__device__ __forceinline__ void r8_dit_inv(v2* buf, int tid) {
    int j = tid & (Q-1);
    int base = 8*tid - 7*j;
    v2 t[8];
    #pragma unroll
    for (int k = 0; k < 8; ++k) t[k] = buf[SW(base + k*Q)];
    apply_tw_inv(t, 6.2831853072f / (float)(8*Q), j);
    v2 y[8];
    dft8_inv(t, y);
    #pragma unroll
    for (int m = 0; m < 8; ++m) buf[SW(base + m*Q)] = y[m];
    if (BAR) __syncthreads();
    else     __builtin_amdgcn_wave_barrier();
}

// ---- radix-8 DIF pass, forward, applied to BOTH 4096-halves of buf.
template<int Q, bool BAR>
__device__ __forceinline__ void r8_dif_fwd(v2* buf, int tid) {
    int j = tid & (Q-1);
    int baseL = 8*tid - 7*j;
    v2 W1=(v2){1.0f,0.0f},W2=W1,W3=W1,W4=W1,W5=W1,W6=W1,W7=W1;
    if (Q > 1) {
        const float fm = -6.2831853072f / (float)(8*Q);
        float sb, cb; __sincosf(fm*(float)j, &sb, &cb);
        W1 = (v2){cb, sb};
        W2 = vcmul(W1,W1); W3 = vcmul(W1,W2); W4 = vcmul(W2,W2);
        W5 = vcmul(W2,W3); W6 = vcmul(W3,W3); W7 = vcmul(W3,W4);
    }
    #pragma unroll 1
    for (int hh = 0; hh < 2; ++hh) {
        int base = baseL + (hh << 12);
        v2 t[8];
        #pragma unroll
        for (int k = 0; k < 8; ++k) t[k] = buf[SW(base + k*Q)];
        v2 y[8];
        dft8_fwd(t, y);
        if (Q > 1) {
            y[1]=vcmul(y[1],W1); y[2]=vcmul(y[2],W2); y[3]=vcmul(y[3],W3);
            y[4]=vcmul(y[4],W4); y[5]=vcmul(y[5],W5); y[6]=vcmul(y[6],W6);
            y[7]=vcmul(y[7],W7);
        }
        #pragma unroll
        for (int m = 0; m < 8; ++m) buf[SW(base + m*Q)] = y[m];
    }
    if (BAR) __syncthreads();
    else     __builtin_amdgcn_wave_barrier();
}

// ---- prep kernel: per-(h,n) Cauchy weights -> workspace (wave-uniform s_load
// source for the main kernel's P1). ws8: 8 floats/entry, ws1: 1 float/entry.
__global__ void __launch_bounds__(64)
s4_prep(const float* __restrict__ Lre, const float* __restrict__ Lim,
        const float* __restrict__ Pre, const float* __restrict__ Pim,
        const float* __restrict__ Bre, const float* __restrict__ Bim,
        const float* __restrict__ Cin,
        float* __restrict__ ws8, float* __restrict__ ws1)
{
    int idx = blockIdx.x*64 + threadIdx.x;   // h*64 + n
    float lre = fminf(Lre[idx], -1e-4f);
    float lim = Lim[idx];
    float pr = Pre[idx], pi = Pim[idx];
    float br = Bre[idx], bi = Bim[idx];
    float cr = Cin[2*idx], ci = Cin[2*idx+1];
    v2 cc = (v2){cr, -ci};
    v2 w00 = vcmul(cc, (v2){br, bi});     // conj(C)*B
    v2 w01 = vcmul(cc, (v2){pr, pi});     // conj(C)*P
    v2 w10 = vcmul((v2){pr,-pi}, (v2){br, bi});  // conj(P)*B
    float* o = ws8 + idx*8;
    o[0] = -lre;  o[1] = -lim;
    o[2] = w00.x; o[3] = w00.y;
    o[4] = w01.x; o[5] = w01.y;
    o[6] = w10.x; o[7] = w10.y;
    ws1[idx] = pr*pr + pi*pi;             // |P|^2 (real weight of k11)
}

// Fused S4 layer, one block per channel h. R11 structure plus:
//  - DIF-Q512 fused into P3 (same-thread addresses: Q512 j=tid, base=tid reads
//    exactly the tid+512k slots P3's thread writes) -> one fewer standalone pass.
//  - Q64/Q8/Q1 passes are wave-local: block barriers between them replaced by
//    free compiler fences.
__global__ void __launch_bounds__(NT)
s4_fused(const float* __restrict__ u,
         const float* __restrict__ Din, const float* __restrict__ logstep,
         const float* __restrict__ ws8, const float* __restrict__ ws1,
         float* __restrict__ out)
{
    __shared__ v2 buf[8192];   // 64 KB -> 2 blocks/CU
    const int tid = threadIdx.x;
    const int h = blockIdx.x;

    const float step = expf(logstep[h]);
    const float tos  = 2.0f / step;
    const float hstep = 0.5f * step;
    const float* pp = ws8 + (h*64)*8;   // wave-uniform -> s_load
    const float* pw = ws1 + h*64;

    // ---- P1: Cauchy kernel; hp0's 4 results staged raw in LDS, hp1's kept in
    //      regs; then the P2 Q=1 butterfly runs in registers. ----
    v2 a4[4];
    #pragma unroll 1
    for (int hp = 0; hp < 2; ++hp) {
        float tv[4];
        v2 cf[4], k00[4], k01[4], k10[4], k11[4];
        const int lbase = hp*(4*NT);
        #pragma unroll
        for (int i = 0; i < 4; ++i) {
            int l = lbase + i*NT + tid;
            // reference's f32 angle; g = i*t with t = -tos*tan(ang/2) (exact identity:
            // (1-e^{i ang})/(1+e^{i ang}) = -i tan(ang/2))
            float ang = -6.2831855f * ((float)l * (1.0f/4096.0f));
            float sh, ch; __sincosf(0.5f*ang, &sh, &ch);
            float traw = -tos * sh * __builtin_amdgcn_rcpf(ch);
            float t = fminf(fmaxf(traw, -1e18f), 1e18f);   // guard cos==0 -> inf*0 NaN
            tv[i] = t;
            cf[i] = (v2){1.0f, t*hstep};                   // c = 1 - i*tan(ang/2)
            k00[i]=(v2)(0.0f); k01[i]=(v2)(0.0f); k10[i]=(v2)(0.0f); k11[i]=(v2)(0.0f);
        }
        #pragma unroll 4
        for (int n = 0; n < 64; ++n) {
            float nlre = pp[n*8+0], nlim = pp[n*8+1];      // scalar pipe (s_load_dwordx8)
            v2 w00 = (v2){pp[n*8+2], pp[n*8+3]};
            v2 w01 = (v2){pp[n*8+4], pp[n*8+5]};
            v2 w10 = (v2){pp[n*8+6], pp[n*8+7]};
            float w11r = pw[n];
            float lre2 = nlre*nlre;
            #pragma unroll
            for (int i = 0; i < 4; ++i) {
                float s = tv[i] + nlim;                    // t - lim
                float inv = __builtin_amdgcn_rcpf(__builtin_fmaf(s, s, lre2));
                v2 p = (v2){nlre, s} * inv;                // d*inv, d = g - lam = (-lre, t-lim)
                v2 cp = (v2){p.x, -p.y};                   // 1/(g-lam)
                v2 rp = (v2){p.y,  p.x};
                k00[i] = vfma1(w00.y, rp, vfma1(w00.x, cp, k00[i]));
                k01[i] = vfma1(w01.y, rp, vfma1(w01.x, cp, k01[i]));
                k10[i] = vfma1(w10.y, rp, vfma1(w10.x, cp, k10[i]));
                k11[i] = vfma1(w11r,  cp, k11[i]);
            }
        }
        #pragma unroll
        for (int i = 0; i < 4; ++i) {
            v2 opk = (v2){1.0f + k11[i].x, k11[i].y};
            float iv = __builtin_amdgcn_rcpf(opk.x*opk.x + opk.y*opk.y);
            v2 r11 = vconj(opk) * iv;
            v2 t  = vcmul(vcmul(k01[i], r11), k10[i]);
            v2 res = vcmul(cf[i], k00[i] - t);             // atRoots[l], l = tid+512*(4hp+i)
            if (hp == 0) buf[SW(tid + 512*i)] = res;       // stage raw
            else         a4[i] = res;
        }
    }
    {   // fused P2 Q=1 butterfly: t[k] = atRoots[tid + 512k]
        v2 t[8];
        #pragma unroll
        for (int k = 0; k < 4; ++k) t[k] = buf[SW(tid + 512*k)];   // own raw stage
        #pragma unroll
        for (int k = 0; k < 4; ++k) t[4+k] = a4[k];
        __syncthreads();                    // all raw reads done before any butterfly write
        v2 y[8];
        dft8_inv(t, y);
        int tb8 = 8*rev3(tid);
        #pragma unroll
        for (int m = 0; m < 8; ++m) buf[SW(tb8 + m)] = y[m];
    }
    __syncthreads();                        // Q1 scatter is cross-wave

    // ---- P2: ifft4096 middle passes (Q8->Q64 wave-local; barrier after Q64
    //      because P3 reads tid+512k across regions) ----
    r8_dit_inv<8,  false>(buf, tid);
    r8_dit_inv<64, true >(buf, tid);

    // ---- P3: fused P2-Q512 (DIT) + pack z = u + i*K + r2 stage + DIF-Q512.
    //      Thread tid reads {SW(tid+512k)}, writes the same lower-half slots
    //      (post-butterfly) + virgin upper half: no internal barrier needed. ----
    {
        v2 t[8];
        #pragma unroll
        for (int k = 0; k < 8; ++k) t[k] = buf[SW(tid + 512*k)];
        apply_tw_inv(t, 6.2831853072f / 4096.0f, tid);
        v2 y[8];
        dft8_inv(t, y);                          // y[m].x = K*4096 at l = tid+512m
        float uval[8];
        const float* up = u + h*4096;
        #pragma unroll
        for (int m = 0; m < 8; ++m) uval[m] = up[tid + 512*m];
        // zL[k] = z[tid+512k], zU[k] = z[tid+512k]*W_8192^{-(tid+512k)}
        float s2, c2; __sincosf(-6.2831853072f/8192.0f*(float)tid, &s2, &c2);
        v2 cur0 = (v2){c2, s2};                  // W_8192^{-tid}
        const v2 C16n = (v2){0.92387953f, -0.38268343f};   // e^{-i pi/8} = W_8192^{-512}
        v2 zL[8], zU[8];
        {
            v2 cur = cur0;
            #pragma unroll
            for (int k = 0; k < 8; ++k) {
                zL[k] = (v2){uval[k], y[k].x * (1.0f/4096.0f)};
                zU[k] = vcmul(zL[k], cur);
                cur = vcmul(cur, C16n);
            }
        }
        // DIF-Q512 butterfly in registers; twiddles W_4096^{-tid*m} = (cur0^2)^m
        v2 V1 = vcmul(cur0, cur0);
        v2 V2 = vcmul(V1,V1), V3 = vcmul(V1,V2), V4 = vcmul(V2,V2),
           V5 = vcmul(V2,V3), V6 = vcmul(V3,V3), V7 = vcmul(V3,V4);
        v2 s[8];
        dft8_fwd(zL, s);
        s[1]=vcmul(s[1],V1); s[2]=vcmul(s[2],V2); s[3]=vcmul(s[3],V3);
        s[4]=vcmul(s[4],V4); s[5]=vcmul(s[5],V5); s[6]=vcmul(s[6],V6);
        s[7]=vcmul(s[7],V7);
        #pragma unroll
        for (int m = 0; m < 8; ++m) buf[SW(tid + 512*m)] = s[m];
        dft8_fwd(zU, s);
        s[1]=vcmul(s[1],V1); s[2]=vcmul(s[2],V2); s[3]=vcmul(s[3],V3);
        s[4]=vcmul(s[4],V4); s[5]=vcmul(s[5],V5); s[6]=vcmul(s[6],V6);
        s[7]=vcmul(s[7],V7);
        #pragma unroll
        for (int m = 0; m < 8; ++m) buf[SW(4096 + tid + 512*m)] = s[m];
    }
    __syncthreads();                        // Q512 writes are cross-wave for Q64

    // ---- P4: forward fft8192 remaining stages (Q512 in P3). Wave-local chain;
    //      barrier only after Q1 (P5 gathers globally).
    //      Z[k] lands at ((k&1)<<12) + d8r4(k>>1).
    r8_dif_fwd<64, false>(buf, tid);
    r8_dif_fwd<8,  false>(buf, tid);
    r8_dif_fwd<1,  true >(buf, tid);

    // ---- P5: unpack + multiply + half-size-inverse pack, fused with P6 Q=1
    //      butterfly (v[i] for r = tid+512i are exactly block 8*rev3(tid)'s inputs).
    {
        float sb, cb; __sincosf(6.2831853072f/8192.0f*(float)tid, &sb, &cb);
        v2 cur = (v2){cb, sb};                   // W_8192^{+tid}
        const v2 C16p = (v2){0.92387953f, 0.38268343f};    // e^{+i pi/8}
        v2 v[8];
        #pragma unroll 1
        for (int i = 0; i < 8; ++i) {
            int r  = i*NT + tid;                 // 0..4095
            int k1 = r,        k1c = (8192 - r) & 8191;
            int k2 = r + 4096, k2c = 4096 - r;
            v2 za = buf[SW(((k1 &1)<<12) + d8r4(k1 >>1))];
            v2 zb = buf[SW(((k1c&1)<<12) + d8r4(k1c>>1))];
            v2 zc = buf[SW(((k2 &1)<<12) + d8r4(k2 >>1))];
            v2 zd = buf[SW(((k2c&1)<<12) + d8r4(k2c>>1))];
            v2 U1 = 0.5f*(za + vconj(zb));
            v2 K1 = -0.5f*vrot(za - vconj(zb));
            v2 Yr = vcmul(U1, K1);                               // Y[r]
            v2 U2 = 0.5f*(zc + vconj(zd));
            v2 K2 = -0.5f*vrot(zc - vconj(zd));
            v2 Ys = vcmul(U2, K2);                               // Y[r+4096]
            v[i] = (Yr + Ys) + vrot(vcmul(cur, Yr - Ys));        // A + i*W^r*(Yr-Ys)
            cur = vcmul(cur, C16p);
        }
        __syncthreads();                         // all gathers done before butterfly writes
        v2 y[8];
        dft8_inv(v, y);
        int tb8 = 8*rev3(tid);
        #pragma unroll
        for (int m = 0; m < 8; ++m) buf[SW(tb8 + m)] = y[m];
    }
    __syncthreads();                        // Q1 scatter is cross-wave

    // ---- P6: ifft4096 middle passes ----
    r8_dit_inv<8,  false>(buf, tid);
    r8_dit_inv<64, true >(buf, tid);

    // ---- P7: fused P6-Q512 butterfly + epilogue. Only m<4 (first 4096 reals)
    //      survive the causal-conv truncation. Reads own slots; writes global only. ----
    {
        v2 t[8];
        #pragma unroll
        for (int k = 0; k < 8; ++k) t[k] = buf[SW(tid + 512*k)];
        apply_tw_inv(t, 6.2831853072f / 4096.0f, tid);
        v2 y[8];
        dft8_inv(t, y);
        const float Dh = Din[h];
        const float sc = 1.0f / 8192.0f;
        const v2* u2 = (const v2*)(u + h*4096);
        v2*     out2 = (v2*)(out + h*4096);
        #pragma unroll
        for (int m = 0; m < 4; ++m) {
            int n = tid + 512*m;                 // v2-pair index -> outputs 2n, 2n+1
            out2[n] = sc*y[m] + Dh*u2[n];
        }
    }
}

extern "C" void kernel_launch(void* const* d_in, const int* in_sizes, int n_in,
                              void* d_out, int out_size, void* d_ws, size_t ws_size,
                              hipStream_t stream)
{
    const float* u       = (const float*)d_in[0];
    const float* Lre     = (const float*)d_in[1];
    const float* Lim     = (const float*)d_in[2];
    const float* Pre     = (const float*)d_in[3];
    const float* Pim     = (const float*)d_in[4];
    const float* Bre     = (const float*)d_in[5];
    const float* Bim     = (const float*)d_in[6];
    const float* Cin     = (const float*)d_in[7];
    const float* Din     = (const float*)d_in[8];
    const float* logstep = (const float*)d_in[9];
    float* out = (float*)d_out;
    const int H = in_sizes[8];  // D is [H,1]

    float* ws8 = (float*)d_ws;            // H*64*8 floats
    float* ws1 = ws8 + (size_t)H*64*8;    // H*64 floats  (total ~1.13 MB << ws_size)

    hipLaunchKernelGGL(s4_prep, dim3(H), dim3(64), 0, stream,
                       Lre, Lim, Pre, Pim, Bre, Bim, Cin, ws8, ws1);
    hipLaunchKernelGGL(s4_fused, dim3(H), dim3(NT), 0, stream,
                       u, Din, logstep, ws8, ws1, out);
}

// Round 14
// 155.724 us; speedup vs baseline: 1.1038x; 1.0258x over previous
//
#include <hip/hip_runtime.h>
#include <math.h>

#define NT 512   // threads per block; 512 blocks (one per channel h)

// Packed f32 pair: LLVM lowers arithmetic on this to v_pk_*_f32 (VOP3P) on gfx950.
typedef float v2 __attribute__((ext_vector_type(2)));

__device__ __forceinline__ v2 vrot(v2 a){ return (v2){-a.y, a.x}; }            // i*a
__device__ __forceinline__ v2 vconj(v2 a){ return (v2){a.x, -a.y}; }
__device__ __forceinline__ v2 vcmul(v2 a, v2 b){ return a.x*b + a.y*vrot(b); } // a*b: 2 pk_fma
__device__ __forceinline__ v2 vcmulc(v2 a, v2 b){                              // a*conj(b): 2 pk_fma
    return a.x*(v2){b.x, -b.y} + a.y*(v2){b.y, b.x};
}
__device__ __forceinline__ v2 vfma1(float s, v2 v, v2 acc){                    // acc + s*v: 1 pk_fma
    return (v2){ __builtin_fmaf(s, v.x, acc.x), __builtin_fmaf(s, v.y, acc.y) };
}

// XOR bank swizzle: float2 elements -> bank = (2e)%32 depends on e mod 16.
// SW changes bits 0-3 only => every address stays inside its aligned
// 512-element region (wave-ownership argument relies on this).
__device__ __forceinline__ int SW(int e){ return e ^ (((e>>5) ^ (e>>9)) & 15); }

// base-8 digit reversal of a 12-bit index
__device__ __forceinline__ int d8r4(int x){
    return ((x&7)<<9) | (((x>>3)&7)<<6) | (((x>>6)&7)<<3) | ((x>>9)&7);
}
// base-8 digit reversal of a 9-bit index (thread id <-> butterfly block)
__device__ __forceinline__ int rev3(int t){
    return ((t&7)<<6) | (t&56) | ((t>>6)&7);
}

// ---- load one 7-twiddle row (padded to 8 v2 = 64B) from the global table.
__device__ __forceinline__ void load_row(const v2* twd, int rowIdx, v2 W[7]) {
    const float4* rp4 = (const float4*)(twd + rowIdx*8);
    float4 q0 = rp4[0], q1 = rp4[1], q2 = rp4[2], q3 = rp4[3];
    W[0]=(v2){q0.x,q0.y}; W[1]=(v2){q0.z,q0.w}; W[2]=(v2){q1.x,q1.y};
    W[3]=(v2){q1.z,q1.w}; W[4]=(v2){q2.x,q2.y}; W[5]=(v2){q2.z,q2.w};
    W[6]=(v2){q3.x,q3.y};
}

// ---- 8-point DFT, inverse sign (sigma=+1). y_m = sum_k t_k w^{mk}, w=e^{+i pi/4}
__device__ __forceinline__ void dft8_inv(v2 t[8], v2 y[8]) {
    const float RH = 0.70710678f;
    v2 p  = t[0]+t[4], m  = t[0]-t[4], q  = t[2]+t[6], r  = t[2]-t[6];
    v2 rr = vrot(r);
    v2 E0 = p+q, E2 = p-q, E1 = m+rr, E3 = m-rr;
    v2 p2 = t[1]+t[5], m2 = t[1]-t[5], q2 = t[3]+t[7], r2 = t[3]-t[7];
    v2 rr2 = vrot(r2);
    v2 O0 = p2+q2, O2 = p2-q2, O1 = m2+rr2, O3 = m2-rr2;
    v2 W1O = RH*(O1 + vrot(O1));        // w^1 * O1
    v2 W2O = vrot(O2);                  // w^2 = i
    v2 W3O = vrot(RH*(O3 + vrot(O3)));  // w^3 = i*w
    y[0] = E0 + O0;  y[4] = E0 - O0;
    y[1] = E1 + W1O; y[5] = E1 - W1O;
    y[2] = E2 + W2O; y[6] = E2 - W2O;
    y[3] = E3 + W3O; y[7] = E3 - W3O;
}

// ---- pruned: only y[0..3] (P7 epilogue discards the mirror half).
__device__ __forceinline__ void dft8_inv_lo4(v2 t[8], v2 y[4]) {
    const float RH = 0.70710678f;
    v2 p  = t[0]+t[4], m  = t[0]-t[4], q  = t[2]+t[6], r  = t[2]-t[6];
    v2 rr = vrot(r);
    v2 E0 = p+q, E2 = p-q, E1 = m+rr, E3 = m-rr;
    v2 p2 = t[1]+t[5], m2 = t[1]-t[5], q2 = t[3]+t[7], r2 = t[3]-t[7];
    v2 rr2 = vrot(r2);
    v2 O0 = p2+q2, O2 = p2-q2, O1 = m2+rr2, O3 = m2-rr2;
    v2 W1O = RH*(O1 + vrot(O1));
    v2 W2O = vrot(O2);
    v2 W3O = vrot(RH*(O3 + vrot(O3)));
    y[0] = E0 + O0;
    y[1] = E1 + W1O;
    y[2] = E2 + W2O;
    y[3] = E3 + W3O;
}

// ---- 8-point DFT, forward sign (sigma=-1).
__device__ __forceinline__ void dft8_fwd(v2 t[8], v2 y[8]) {
    const float RH = 0.70710678f;
    v2 p  = t[0]+t[4], m  = t[0]-t[4], q  = t[2]+t[6], r  = t[2]-t[6];
    v2 rr = vrot(r);
    v2 E0 = p+q, E2 = p-q, E1 = m-rr, E3 = m+rr;
    v2 p2 = t[1]+t[5], m2 = t[1]-t[5], q2 = t[3]+t[7], r2 = t[3]-t[7];
    v2 rr2 = vrot(r2);
    v2 O0 = p2+q2, O2 = p2-q2, O1 = m2-rr2, O3 = m2+rr2;
    v2 W1O = RH*(O1 - vrot(O1));          // w = (1-i)/sqrt2
    v2 W2O = (v2){O2.y, -O2.x};           // w^2 = -i
    v2 W3O = (-RH)*(O3 + vrot(O3));       // w^3 = (-1-i)/sqrt2
    y[0] = E0 + O0;  y[4] = E0 - O0;
    y[1] = E1 + W1O; y[5] = E1 - W1O;
    y[2] = E2 + W2O; y[6] = E2 - W2O;
    y[3] = E3 + W3O; y[7] = E3 - W3O;
}

// Wave-locality: for Q in {1,8,64}, thread t's butterfly addresses lie in the
// aligned 512-elem region [512*(t>>6), +512), owned exclusively by t's wave.
// LDS ops within a wave execute in issue order, so consecutive wave-local
// passes need only a compiler fence. BAR=true emits the block barrier.

// ---- radix-8 DIT pass, inverse, in-place over 4096 elems.
// Twiddle row from global table: W_{8Q}^{j(k+1)} = twd[(512/Q)*j][k].
template<int Q, bool BAR>
__device__ __forceinline__ void r8_dit_inv(v2* buf, int tid, const v2* twd) {
    int j = tid & (Q-1);
    v2 W[7];
    load_row(twd, (512/Q)*j, W);       // issue vmem first, overlap with LDS reads
    int base = 8*tid - 7*j;
    v2 t[8];
    #pragma unroll
    for (int k = 0; k < 8; ++k) t[k] = buf[SW(base + k*Q)];
    #pragma unroll
    for (int k = 0; k < 7; ++k) t[k+1] = vcmul(t[k+1], W[k]);
    v2 y[8];
    dft8_inv(t, y);
    #pragma unroll
    for (int m = 0; m < 8; ++m) buf[SW(base + m*Q)] = y[m];
    if (BAR) __syncthreads();
    else     __builtin_amdgcn_wave_barrier();
}

// ---- radix-8 DIF pass, forward, applied to BOTH 4096-halves of buf.
// Forward twiddles are conj of the table row (vcmulc).
template<int Q, bool BAR>
__device__ __forceinline__ void r8_dif_fwd(v2* buf, int tid, const v2* twd) {
    int j = tid & (Q-1);
    int baseL = 8*tid - 7*j;
    v2 W[7];
    if (Q > 1) load_row(twd, (512/Q)*j, W);
    #pragma unroll 1
    for (int hh = 0; hh < 2; ++hh) {
        int base = baseL + (hh << 12);
        v2 t[8];
        #pragma unroll
        for (int k = 0; k < 8; ++k) t[k] = buf[SW(base + k*Q)];
        v2 y[8];
        dft8_fwd(t, y);
        if (Q > 1) {
            #pragma unroll
            for (int k = 0; k < 7; ++k) y[k+1] = vcmulc(y[k+1], W[k]);
        }
        #pragma unroll
        for (int m = 0; m < 8; ++m) buf[SW(base + m*Q)] = y[m];
    }
    if (BAR) __syncthreads();
    else     __builtin_amdgcn_wave_barrier();
}

// ---- prep kernel 1: per-(h,n) Cauchy weights -> workspace (wave-uniform
// s_load source for the main kernel's P1).
__global__ void __launch_bounds__(64)
s4_prep(const float* __restrict__ Lre, const float* __restrict__ Lim,
        const float* __restrict__ Pre, const float* __restrict__ Pim,
        const float* __restrict__ Bre, const float* __restrict__ Bim,
        const float* __restrict__ Cin,
        float* __restrict__ ws8, float* __restrict__ ws1)
{
    int idx = blockIdx.x*64 + threadIdx.x;   // h*64 + n
    float lre = fminf(Lre[idx], -1e-4f);
    float lim = Lim[idx];
    float pr = Pre[idx], pi = Pim[idx];
    float br = Bre[idx], bi = Bim[idx];
    float cr = Cin[2*idx], ci = Cin[2*idx+1];
    v2 cc = (v2){cr, -ci};
    v2 w00 = vcmul(cc, (v2){br, bi});     // conj(C)*B
    v2 w01 = vcmul(cc, (v2){pr, pi});     // conj(C)*P
    v2 w10 = vcmul((v2){pr,-pi}, (v2){br, bi});  // conj(P)*B
    float* o = ws8 + idx*8;
    o[0] = -lre;  o[1] = -lim;
    o[2] = w00.x; o[3] = w00.y;
    o[4] = w01.x; o[5] = w01.y;
    o[6] = w10.x; o[7] = w10.y;
    ws1[idx] = pr*pr + pi*pi;             // |P|^2 (real weight of k11)
}

// ---- prep kernel 2: twiddle table twd[j][k] = e^{+2pi i j(k+1)/4096},
// j<512, k<7 (row padded to 8). Covers all DIT chains (Q=512: row j;
// Q=64: row 8j; Q=8: row 64j); DIF chains are the conjugates.
__global__ void __launch_bounds__(NT)
s4_twprep(v2* __restrict__ twd)
{
    int j = threadIdx.x;
    const float fm = 6.2831853072f / 4096.0f;
    #pragma unroll
    for (int k = 0; k < 7; ++k) {
        float s, c; __sincosf(fm * (float)(j*(k+1)), &s, &c);
        twd[j*8 + k] = (v2){c, s};
    }
    twd[j*8 + 7] = (v2){1.0f, 0.0f};
}

// Fused S4 layer, one block per channel h. R12 structure plus: global twiddle
// table (replaces per-butterfly sincos+power chains), P5 index algebra
// (2 digit-reversals instead of 4), pruned P7 DFT.
__global__ void __launch_bounds__(NT)
s4_fused(const float* __restrict__ u,
         const float* __restrict__ Din, const float* __restrict__ logstep,
         const float* __restrict__ ws8, const float* __restrict__ ws1,
         const v2* __restrict__ twd,
         float* __restrict__ out)
{
    __shared__ v2 buf[8192];   // 64 KB -> 2 blocks/CU
    const int tid = threadIdx.x;
    const int h = blockIdx.x;

    const float step = expf(logstep[h]);
    const float tos  = 2.0f / step;
    const float hstep = 0.5f * step;
    const float* pp = ws8 + (h*64)*8;   // wave-uniform -> s_load
    const float* pw = ws1 + h*64;

    // ---- P1: Cauchy kernel; hp0's 4 results staged raw in LDS, hp1's kept in
    //      regs; then the P2 Q=1 butterfly runs in registers. ----
    v2 a4[4];
    #pragma unroll 1
    for (int hp = 0; hp < 2; ++hp) {
        float tv[4];
        v2 cf[4], k00[4], k01[4], k10[4], k11[4];
        const int lbase = hp*(4*NT);
        #pragma unroll
        for (int i = 0; i < 4; ++i) {
            int l = lbase + i*NT + tid;
            // reference's f32 angle; g = i*t with t = -tos*tan(ang/2) (exact identity:
            // (1-e^{i ang})/(1+e^{i ang}) = -i tan(ang/2))
            float ang = -6.2831855f * ((float)l * (1.0f/4096.0f));
            float sh, ch; __sincosf(0.5f*ang, &sh, &ch);
            float traw = -tos * sh * __builtin_amdgcn_rcpf(ch);
            float t = fminf(fmaxf(traw, -1e18f), 1e18f);   // guard cos==0 -> inf*0 NaN
            tv[i] = t;
            cf[i] = (v2){1.0f, t*hstep};                   // c = 1 - i*tan(ang/2)
            k00[i]=(v2)(0.0f); k01[i]=(v2)(0.0f); k10[i]=(v2)(0.0f); k11[i]=(v2)(0.0f);
        }
        #pragma unroll 4
        for (int n = 0; n < 64; ++n) {
            float nlre = pp[n*8+0], nlim = pp[n*8+1];      // scalar pipe (s_load_dwordx8)
            v2 w00 = (v2){pp[n*8+2], pp[n*8+3]};
            v2 w01 = (v2){pp[n*8+4], pp[n*8+5]};
            v2 w10 = (v2){pp[n*8+6], pp[n*8+7]};
            float w11r = pw[n];
            float lre2 = nlre*nlre;
            #pragma unroll
            for (int i = 0; i < 4; ++i) {
                float s = tv[i] + nlim;                    // t - lim
                float inv = __builtin_amdgcn_rcpf(__builtin_fmaf(s, s, lre2));
                v2 p = (v2){nlre, s} * inv;                // d*inv, d = g - lam = (-lre, t-lim)
                v2 cp = (v2){p.x, -p.y};                   // 1/(g-lam)
                v2 rp = (v2){p.y,  p.x};
                k00[i] = vfma1(w00.y, rp, vfma1(w00.x, cp, k00[i]));
                k01[i] = vfma1(w01.y, rp, vfma1(w01.x, cp, k01[i]));
                k10[i] = vfma1(w10.y, rp, vfma1(w10.x, cp, k10[i]));
                k11[i] = vfma1(w11r,  cp, k11[i]);
            }
        }
        #pragma unroll
        for (int i = 0; i < 4; ++i) {
            v2 opk = (v2){1.0f + k11[i].x, k11[i].y};
            float iv = __builtin_amdgcn_rcpf(opk.x*opk.x + opk.y*opk.y);
            v2 r11 = vconj(opk) * iv;
            v2 t  = vcmul(vcmul(k01[i], r11), k10[i]);
            v2 res = vcmul(cf[i], k00[i] - t);             // atRoots[l], l = tid+512*(4hp+i)
            if (hp == 0) buf[SW(tid + 512*i)] = res;       // stage raw
            else         a4[i] = res;
        }
    }
    {   // fused P2 Q=1 butterfly: t[k] = atRoots[tid + 512k]
        v2 t[8];
        #pragma unroll
        for (int k = 0; k < 4; ++k) t[k] = buf[SW(tid + 512*k)];   // own raw stage
        #pragma unroll
        for (int k = 0; k < 4; ++k) t[4+k] = a4[k];
        __syncthreads();                    // all raw reads done before any butterfly write
        v2 y[8];
        dft8_inv(t, y);
        int tb8 = 8*rev3(tid);
        #pragma unroll
        for (int m = 0; m < 8; ++m) buf[SW(tb8 + m)] = y[m];
    }
    __syncthreads();                        // Q1 scatter is cross-wave

    // ---- P2: ifft4096 middle passes (Q8->Q64 wave-local) ----
    r8_dit_inv<8,  false>(buf, tid, twd);
    r8_dit_inv<64, true >(buf, tid, twd);

    // ---- P3: fused P2-Q512 (DIT) + pack z = u + i*K + r2 stage + DIF-Q512.
    //      Thread tid reads {SW(tid+512k)}, writes the same lower-half slots
    //      (post-butterfly) + virgin upper half: no internal barrier needed. ----
    {
        v2 W[7];
        load_row(twd, tid, W);              // W[k] = W_4096^{+tid(k+1)}
        v2 t[8];
        #pragma unroll
        for (int k = 0; k < 8; ++k) t[k] = buf[SW(tid + 512*k)];
        #pragma unroll
        for (int k = 0; k < 7; ++k) t[k+1] = vcmul(t[k+1], W[k]);
        v2 y[8];
        dft8_inv(t, y);                          // y[m].x = K*4096 at l = tid+512m
        float uval[8];
        const float* up = u + h*4096;
        #pragma unroll
        for (int m = 0; m < 8; ++m) uval[m] = up[tid + 512*m];
        // zL[k] = z[tid+512k], zU[k] = z[tid+512k]*W_8192^{-(tid+512k)}
        float s2, c2; __sincosf(-6.2831853072f/8192.0f*(float)tid, &s2, &c2);
        v2 cur0 = (v2){c2, s2};                  // W_8192^{-tid}
        const v2 C16n = (v2){0.92387953f, -0.38268343f};   // e^{-i pi/8} = W_8192^{-512}
        v2 zL[8], zU[8];
        {
            v2 cur = cur0;
            #pragma unroll
            for (int k = 0; k < 8; ++k) {
                zL[k] = (v2){uval[k], y[k].x * (1.0f/4096.0f)};
                zU[k] = vcmul(zL[k], cur);
                cur = vcmul(cur, C16n);
            }
        }
        // DIF-Q512 butterfly in registers; twiddles W_4096^{-tid*m} = conj(W[m-1])
        v2 s[8];
        dft8_fwd(zL, s);
        #pragma unroll
        for (int m = 1; m < 8; ++m) s[m] = vcmulc(s[m], W[m-1]);
        #pragma unroll
        for (int m = 0; m < 8; ++m) buf[SW(tid + 512*m)] = s[m];
        dft8_fwd(zU, s);
        #pragma unroll
        for (int m = 1; m < 8; ++m) s[m] = vcmulc(s[m], W[m-1]);
        #pragma unroll
        for (int m = 0; m < 8; ++m) buf[SW(4096 + tid + 512*m)] = s[m];
    }
    __syncthreads();                        // Q512 writes are cross-wave for Q64

    // ---- P4: forward fft8192 remaining stages (Q512 in P3). Wave-local chain;
    //      barrier only after Q1. Z[k] lands at ((k&1)<<12) + d8r4(k>>1).
    r8_dif_fwd<64, false>(buf, tid, twd);
    r8_dif_fwd<8,  false>(buf, tid, twd);
    r8_dif_fwd<1,  true >(buf, tid, twd);

    // ---- P5: unpack + multiply + half-size-inverse pack, fused with P6 Q=1
    //      butterfly (v[i] for r = tid+512i are exactly block 8*rev3(tid)'s inputs).
    //      Index algebra: e(zc)=e(za)+4, e(zb)=e(zd)+4 (top-octal-digit of the
    //      pre-reversal index: +2048 -> reversed +4; r=0 fixed by cndmask). ----
    {
        float sb, cb; __sincosf(6.2831853072f/8192.0f*(float)tid, &sb, &cb);
        v2 cur = (v2){cb, sb};                   // W_8192^{+tid}
        const v2 C16p = (v2){0.92387953f, 0.38268343f};    // e^{+i pi/8}
        v2 v[8];
        #pragma unroll 1
        for (int i = 0; i < 8; ++i) {
            int r  = i*NT + tid;                 // 0..4095
            int par = (r&1)<<12;
            int e1 = par + d8r4(r>>1);           // za: Z[r]
            int e3 = e1 + 4;                     // zc: Z[r+4096]
            int k2c = 4096 - r;
            int e4 = ((k2c&1)<<12) + d8r4((k2c>>1)&4095);  // zd: Z[4096-r]
            int e2 = (r == 0) ? 0 : (e4 + 4);    // zb: Z[(8192-r)&8191]
            v2 za = buf[SW(e1)];
            v2 zb = buf[SW(e2)];
            v2 zc = buf[SW(e3)];
            v2 zd = buf[SW(e4)];
            v2 U1 = 0.5f*(za + vconj(zb));
            v2 K1 = -0.5f*vrot(za - vconj(zb));
            v2 Yr = vcmul(U1, K1);                               // Y[r]
            v2 U2 = 0.5f*(zc + vconj(zd));
            v2 K2 = -0.5f*vrot(zc - vconj(zd));
            v2 Ys = vcmul(U2, K2);                               // Y[r+4096]
            v[i] = (Yr + Ys) + vrot(vcmul(cur, Yr - Ys));        // A + i*W^r*(Yr-Ys)
            cur = vcmul(cur, C16p);
        }
        __syncthreads();                         // all gathers done before butterfly writes
        v2 y[8];
        dft8_inv(v, y);
        int tb8 = 8*rev3(tid);
        #pragma unroll
        for (int m = 0; m < 8; ++m) buf[SW(tb8 + m)] = y[m];
    }
    __syncthreads();                        // Q1 scatter is cross-wave

    // ---- P6: ifft4096 middle passes ----
    r8_dit_inv<8,  false>(buf, tid, twd);
    r8_dit_inv<64, true >(buf, tid, twd);

    // ---- P7: fused P6-Q512 butterfly + epilogue. Only m<4 (first 4096 reals)
    //      survive the causal-conv truncation -> pruned DFT. ----
    {
        v2 W[7];
        load_row(twd, tid, W);
        v2 t[8];
        #pragma unroll
        for (int k = 0; k < 8; ++k) t[k] = buf[SW(tid + 512*k)];
        #pragma unroll
        for (int k = 0; k < 7; ++k) t[k+1] = vcmul(t[k+1], W[k]);
        v2 y[4];
        dft8_inv_lo4(t, y);
        const float Dh = Din[h];
        const float sc = 1.0f / 8192.0f;
        const v2* u2 = (const v2*)(u + h*4096);
        v2*     out2 = (v2*)(out + h*4096);
        #pragma unroll
        for (int m = 0; m < 4; ++m) {
            int n = tid + 512*m;                 // v2-pair index -> outputs 2n, 2n+1
            out2[n] = sc*y[m] + Dh*u2[n];
        }
    }
}

extern "C" void kernel_launch(void* const* d_in, const int* in_sizes, int n_in,
                              void* d_out, int out_size, void* d_ws, size_t ws_size,
                              hipStream_t stream)
{
    const float* u       = (const float*)d_in[0];
    const float* Lre     = (const float*)d_in[1];
    const float* Lim     = (const float*)d_in[2];
    const float* Pre     = (const float*)d_in[3];
    const float* Pim     = (const float*)d_in[4];
    const float* Bre     = (const float*)d_in[5];
    const float* Bim     = (const float*)d_in[6];
    const float* Cin     = (const float*)d_in[7];
    const float* Din     = (const float*)d_in[8];
    const float* logstep = (const float*)d_in[9];
    float* out = (float*)d_out;
    const int H = in_sizes[8];  // D is [H,1]

    float* ws8 = (float*)d_ws;            // H*64*8 floats (1 MB)
    float* ws1 = ws8 + (size_t)H*64*8;    // H*64 floats (128 KB)
    v2*    twd = (v2*)(ws1 + (size_t)H*64);  // 512 rows x 8 v2 (32 KB); 64B-aligned

    hipLaunchKernelGGL(s4_prep, dim3(H), dim3(64), 0, stream,
                       Lre, Lim, Pre, Pim, Bre, Bim, Cin, ws8, ws1);
    hipLaunchKernelGGL(s4_twprep, dim3(1), dim3(NT), 0, stream, twd);
    hipLaunchKernelGGL(s4_fused, dim3(H), dim3(NT), 0, stream,
                       u, Din, logstep, ws8, ws1, twd, out);
}